// Round 3
// baseline (207.224 us; speedup 1.0000x reference)
//
#include <hip/hip_runtime.h>
#include <math.h>

#define NQ 12
#define NL 6
#define TPB 64

// ---------------------------------------------------------------------------
// R11: single-wave blocks + XOR-diagonal storage — no LDS state, no barriers.
//
// Storage A (layer entry): element (hi = label bits 6..11, lo = bits 0..5)
// lives at lane lo, reg d = hi^lo.  Storage B (post-T1): lane hi, reg d.
// label bit m <-> wire 11-m (canonical, same as R10-verified).
//
//  h1: RY wires 5..0  = hi bits k -> reg pairs (d, d^bk); since
//      hi_k = d_k ^ lane_k, the s-coefficient sign flips with lane bit k:
//      u' = c*u + S*w, w' = c*w - S*u, S = lane_k ? s : -s.
//  T1: A->B is ONE ds_bpermute per reg: v[d] <- lane (L^d), same reg.
//  h2: RY wires 11..6 = lo bits; identical structure (lo_k = d_k ^ lane_k).
//  diag (l<5): merged D_om(l)*D_phi(l+1) at post-CNOT label gray12(lambda),
//      SAME tables as R10 (verified): W[l][hi] lane factor (global load),
//      Z[l][lam6][lo] gathered from a 5KB LDS copy at index lo = d^L.
//  fold+T2: B(lambda) -> A'(mu=gray12(lambda)) =
//      (a) lane-parity reg swap r<->r^63 on odd lanes (lam_hi odd), then
//      (b) per-reg bpermute: new[e] <- swapped[g6inv(e)] pulled from lane
//          g6inv(e)^g6inv(L) — walked along compile-time cycles of g6inv
//          (in-place, 1 temp per cycle). Derivation verified on worked
//          examples (lambda=0, 64, 128, 192).
//  Last layer: skip diag+fold (diagonals don't affect |amp|^2); epilogue in
//  B-storage: post-CNOT wire0 = lane bit5, wire1 = lane bits 4^5 (as R10).
//
// LDS = 5120 B (Z tables only), zero __syncthreads. 2048 blocks = 8/CU =
// 2 waves/SIMD all-resident; VGPR ~150 allows 3/SIMD.
// ---------------------------------------------------------------------------

// ---- d_ws layout (float offsets) — identical to R10 (prep verified) ----
#define WS_WA0 0        // 64 f2 : init lane factor e^{i(phi0_lane - pi/2*pop)}
#define WS_Z0  128      // 64 f2 : init hi factor   e^{i(phi0_hi  - pi/2*pop)}
#define WS_W   256      // 5*64 f2 : merged diag lane(=hi) factor
#define WS_Z   896      // 5*2*64 f2 : merged diag lo-table [l][lam6][lo]
#define WS_RYT 2176     // 72 float4 : (c,c,s,s) per (l,wire)

typedef float f2 __attribute__((ext_vector_type(2)));

static __device__ __forceinline__ f2 pk_mul(f2 a, f2 b) {
  f2 d; asm("v_pk_mul_f32 %0, %1, %2" : "=v"(d) : "v"(a), "v"(b)); return d;
}
static __device__ __forceinline__ f2 pk_fma(f2 a, f2 b, f2 c) {
  f2 d; asm("v_pk_fma_f32 %0, %1, %2, %3" : "=v"(d) : "v"(a), "v"(b), "v"(c)); return d;
}
// complex mul, both operands packed (re,im)
static __device__ __forceinline__ f2 cmulp(f2 a, f2 c) {
  f2 r1, d;
  asm("v_pk_mul_f32 %0, %1, %2 op_sel:[0,0] op_sel_hi:[0,1]"
      : "=v"(r1) : "v"(a), "v"(c));
  asm("v_pk_fma_f32 %0, %1, %2, %3 op_sel:[1,1,0] op_sel_hi:[1,0,1] neg_lo:[1,0,0]"
      : "=v"(d) : "v"(a), "v"(c), "v"(r1));
  return d;
}
// 64-lane gather: dst lane i <- src value on lane (addr>>2)
static __device__ __forceinline__ f2 bp2(int addr, f2 s) {
  f2 d;
  d.x = __int_as_float(__builtin_amdgcn_ds_bpermute(addr, __float_as_int(s.x)));
  d.y = __int_as_float(__builtin_amdgcn_ds_bpermute(addr, __float_as_int(s.y)));
  return d;
}

// RY with lane-signed s: u' = c*u + S*w ; w' = c*w - S*u  (S = +-s per lane)
template<int BIT>
static __device__ __forceinline__ void apply_ry64(f2 v[64], f2 cc, f2 SS) {
  #pragma unroll
  for (int j = 0; j < 64; ++j) {
    if (j & (1 << BIT)) continue;
    const int k = j | (1 << BIT);
    f2 a = v[j], b = v[k];
    f2 t1 = pk_mul(a, cc);
    f2 t2 = pk_mul(b, cc);
    v[j] = pk_fma(b, SS, t1);
    f2 nb;
    asm("v_pk_fma_f32 %0, %1, %2, %3 neg_lo:[1,0,0] neg_hi:[1,0,0]"
        : "=v"(nb) : "v"(a), "v"(SS), "v"(t2));
    v[k] = nb;
  }
}

// ---------------------------------------------------------------------------
// Prep kernel — verbatim R10 (numerically verified by R10's passing run).
// ---------------------------------------------------------------------------
__global__ __launch_bounds__(256)
void qprep_kernel(const float* __restrict__ w, float* __restrict__ ws) {
  const int t = threadIdx.x;
  const float HPI = 1.57079632679489662f;

  if (t < 64) {              // WA0[u], u = label bits 0..5 <-> wires 11..6
    const int u = t;
    float f = 0.f;
    #pragma unroll
    for (int k = 0; k < 6; ++k) {
      float p = w[(0*NQ + (11-k))*3 + 0];
      f += ((u >> k) & 1) ? 0.5f*p : -0.5f*p;
    }
    f -= HPI * (float)__popc(u);
    float sv, cv; sincosf(f, &sv, &cv);
    ws[WS_WA0 + 2*u] = cv; ws[WS_WA0 + 2*u + 1] = sv;
  } else if (t < 128) {      // Z0[p], p = label bits 6..11 <-> wires 5..0
    const int p_ = t - 64;
    float f = 0.f;
    #pragma unroll
    for (int k = 0; k < 6; ++k) {
      float p = w[(0*NQ + (5-k))*3 + 0];
      f += ((p_ >> k) & 1) ? 0.5f*p : -0.5f*p;
    }
    f -= HPI * (float)__popc(p_);
    float sv, cv; sincosf(f, &sv, &cv);
    ws[WS_Z0 + 2*p_] = cv; ws[WS_Z0 + 2*p_ + 1] = sv;
  }

  // W[l][u], u = hi = label bits 6..11 (u_k <-> wire 5-k):
  //   om(l) over u_k; phi(l+1) over gray bits g_{6+k} = u_k^u_{k+1} (g11=u5)
  for (int idx = t; idx < 5*64; idx += 256) {
    const int l = idx >> 6, u = idx & 63;
    float f = 0.f;
    #pragma unroll
    for (int k = 0; k < 6; ++k) {
      float om = w[(l*NQ + (5-k))*3 + 2];
      f += ((u >> k) & 1) ? 0.5f*om : -0.5f*om;
    }
    const int gu = u ^ (u >> 1);
    #pragma unroll
    for (int k = 0; k < 6; ++k) {
      float ph = w[((l+1)*NQ + (5-k))*3 + 0];
      f += ((gu >> k) & 1) ? 0.5f*ph : -0.5f*ph;
    }
    float sv, cv; sincosf(f, &sv, &cv);
    ws[WS_W + 2*idx] = cv; ws[WS_W + 2*idx + 1] = sv;
  }

  // Z[l][h][p], p = lo = label bits 0..5 (p_k <-> wire 11-k), h = lam6:
  //   om(l) over p_k; phi(l+1) over g_k = p_k^p_{k+1} (k<5), g5 = p5^h
  for (int idx = t; idx < 5*2*64; idx += 256) {
    const int l = idx >> 7, h = (idx >> 6) & 1, p_ = idx & 63;
    float f = 0.f;
    #pragma unroll
    for (int k = 0; k < 6; ++k) {
      float om = w[(l*NQ + (11-k))*3 + 2];
      f += ((p_ >> k) & 1) ? 0.5f*om : -0.5f*om;
    }
    const int gp = (p_ ^ (p_ >> 1)) ^ (h << 5);
    #pragma unroll
    for (int k = 0; k < 6; ++k) {
      float ph = w[((l+1)*NQ + (11-k))*3 + 0];
      f += ((gp >> k) & 1) ? 0.5f*ph : -0.5f*ph;
    }
    float sv, cv; sincosf(f, &sv, &cv);
    ws[WS_Z + 2*idx] = cv; ws[WS_Z + 2*idx + 1] = sv;
  }

  if (t < NL*NQ) {           // ryt: (c,c,s,s) of theta/2 per (l,wire)
    float sv, cv; sincosf(0.5f*w[t*3 + 1], &sv, &cv);
    ((float4*)(ws + WS_RYT))[t] = make_float4(cv, cv, sv, sv);
  }
}

// fold cycle-walk macros: new[e] <- swapped[g6inv(e)], pulled from lane
// g6inv(e)^g6inv(L); addr = vgi ^ (SRC<<2) since SRC = g6inv(DST).
#define STEP(DST, SRC) v[DST] = bp2(vgi ^ ((SRC) << 2), v[SRC]);
#define CYC2(A,B) { f2 t_ = v[A]; STEP(A,B); v[B] = bp2(vgi ^ ((A) << 2), t_); }
#define CYC4(A,B,C,D) { f2 t_ = v[A]; STEP(A,B); STEP(B,C); STEP(C,D); \
                        v[D] = bp2(vgi ^ ((A) << 2), t_); }
#define CYC8(A,B,C,D,E,F,G,H) { f2 t_ = v[A]; STEP(A,B); STEP(B,C); STEP(C,D); \
                        STEP(D,E); STEP(E,F); STEP(F,G); STEP(G,H); \
                        v[H] = bp2(vgi ^ ((A) << 2), t_); }

// ---------------------------------------------------------------------------
// Main kernel: 1 wave per block, XOR-diag storage, 64 amps per lane.
// ---------------------------------------------------------------------------
__global__ __launch_bounds__(TPB, 2)
void qsim12_kernel(const float* __restrict__ x, const float* __restrict__ ws,
                   float* __restrict__ out) {
  __shared__ __align__(16) float zt[5*2*64*2];   // 5120 B Z-table copy
  const int L = threadIdx.x;
  const int b = blockIdx.x;

  // copy Z tables to LDS (coalesced; single wave -> lgkmcnt ordering only)
  #pragma unroll
  for (int i = 0; i < 10; ++i)
    ((f2*)zt)[i*64 + L] = *(const f2*)(ws + WS_Z + 2*(i*64 + L));

  // x cos/sin: lanes 0..11 compute, readlane broadcast
  float csx[NQ], csy[NQ];
  {
    float xv = (L < NQ) ? x[b*NQ + L] : 0.f;
    float sv, cv; sincosf(0.5f*xv, &sv, &cv);
    #pragma unroll
    for (int q = 0; q < NQ; ++q) {
      csx[q] = __int_as_float(__builtin_amdgcn_readlane(__float_as_int(cv), q));
      csy[q] = __int_as_float(__builtin_amdgcn_readlane(__float_as_int(sv), q));
    }
  }

  f2 v[64];
  const int lb = L << 2;

  // ---- Init (A-storage): v[d]@lane L = element(hi=d^L, lo=L)
  //   = rl(L)*WA0(L) * m(hi)*Z0(hi), hi-part pulled by XOR shuffle.
  {
    float rl = 1.f;
    #pragma unroll
    for (int k = 0; k < 6; ++k)
      rl *= ((L >> k) & 1) ? csy[11-k] : csx[11-k];
    float mh = 1.f;
    #pragma unroll
    for (int k = 0; k < 6; ++k)
      mh *= ((L >> k) & 1) ? csy[5-k] : csx[5-k];
    const float2 z0 = *(const float2*)(ws + WS_Z0 + 2*L);
    const float2 w0 = *(const float2*)(ws + WS_WA0 + 2*L);
    const f2 zm = (f2){z0.x*mh, z0.y*mh};     // lane L holds hi=L factor
    const f2 a0 = (f2){w0.x*rl, w0.y*rl};
    #pragma unroll
    for (int d = 0; d < 64; ++d)
      v[d] = cmulp(a0, bp2(lb ^ (d << 2), zm));
  }

  // g6inv(L) byte addr (suffix-xor) + parity for the fold
  int gi = L; gi ^= gi >> 1; gi ^= gi >> 2; gi ^= gi >> 4;
  const int vgi = gi << 2;
  const bool oddl = (L & 1) != 0;

  #define RYS(BIT, WQ) { \
    const float4 r_ = *(const float4*)(ws + WS_RYT + 4*(l*NQ + (WQ)));   \
    const float S_ = ((L >> (BIT)) & 1) ? r_.z : -r_.z;                  \
    apply_ry64<BIT>(v, (f2){r_.x, r_.x}, (f2){S_, S_}); }

  #pragma unroll 1
  for (int l = 0; l < NL; ++l) {
    // h1: wires 5..0 (hi bits 0..5)
    RYS(0,5) RYS(1,4) RYS(2,3) RYS(3,2) RYS(4,1) RYS(5,0)

    // T1: A->B, per-reg XOR-lane shuffle (in-place safe)
    #pragma unroll
    for (int d = 0; d < 64; ++d)
      v[d] = bp2(lb ^ (d << 2), v[d]);

    // h2: wires 11..6 (lo bits 0..5)
    RYS(0,11) RYS(1,10) RYS(2,9) RYS(3,8) RYS(4,7) RYS(5,6)

    if (l < NL-1) {
      // merged diag at post-CNOT label gray12(lambda): lane(=hi) factor W,
      // lo-table Z gathered at index lo = d^L with lam6 = lane bit 0 select
      const float2 wv = *(const float2*)(ws + WS_W + (l*64 + L)*2);
      const f2 W = (f2){wv.x, wv.y};
      const int zb = ((l*2 + (L & 1)) << 9) + (L << 3);   // byte base
      #pragma unroll
      for (int d = 0; d < 64; ++d) {
        const f2 z = *(const f2*)((const char*)zt + (zb ^ (d << 3)));
        v[d] = cmulp(cmulp(v[d], z), W);
      }

      // fold step (a): odd lanes (lam_hi odd) swap regs r <-> r^63
      #pragma unroll
      for (int r = 0; r < 32; ++r) {
        const f2 a = v[r], c = v[63 - r];
        v[r]      = oddl ? c : a;
        v[63 - r] = oddl ? a : c;
      }
      // fold step (b): per-reg bpermute along g6inv cycles (in-place)
      STEP(0,0) STEP(1,1)
      CYC2(2,3)
      CYC4(4,7,5,6)
      CYC4(8,15,10,12)
      CYC4(9,14,11,13)
      CYC8(16,31,21,25,17,30,20,24)
      CYC8(18,28,23,26,19,29,22,27)
      CYC8(32,63,42,51,34,60,40,48)
      CYC8(33,62,43,50,35,61,41,49)
      CYC8(36,56,47,53,38,59,45,54)
      CYC8(37,57,46,52,39,58,44,55)
    }
  }

  // ---- Epilogue (B-storage: lane = hi = label bits 6..11).
  // post-CNOT wire0 = lam11 = L5; wire1 = lam10^lam11 = L4^L5.
  float ssum = 0.f;
  #pragma unroll
  for (int p = 0; p < 64; ++p)
    ssum += v[p].x*v[p].x + v[p].y*v[p].y;
  float s0 = ((L >> 5) & 1) ? -ssum : ssum;
  float s1 = (((L >> 4) ^ (L >> 5)) & 1) ? -ssum : ssum;
  #pragma unroll
  for (int off = 32; off >= 1; off >>= 1) {
    s0 += __shfl_down(s0, off);
    s1 += __shfl_down(s1, off);
  }
  if (L == 0) { out[b*2 + 0] = s0; out[b*2 + 1] = s1; }
}

extern "C" void kernel_launch(void* const* d_in, const int* in_sizes, int n_in,
                              void* d_out, int out_size, void* d_ws, size_t ws_size,
                              hipStream_t stream) {
  const float* x = (const float*)d_in[0];      // (B, 12) f32
  const float* w = (const float*)d_in[1];      // (6, 12, 3) f32
  float* out = (float*)d_out;                  // (B, 2) f32
  float* ws = (float*)d_ws;                    // needs >= 9856 B
  int B = in_sizes[0] / NQ;
  qprep_kernel<<<1, 256, 0, stream>>>(w, ws);
  qsim12_kernel<<<B, TPB, 0, stream>>>(x, ws, out);
}

// Round 4
// 162.538 us; speedup vs baseline: 1.2749x; 1.2749x over previous
//
#include <hip/hip_runtime.h>
#include <math.h>

#define NQ 12
#define DIM 4096
#define NL 6
#define TPB 128

// ---------------------------------------------------------------------------
// R12: R10's verified single-wave pipeline x 2 waves/block sharing one 32 KB
// LDS buffer (each wave = its own batch element).
//
// R10 (verified correct at 111 us) stalled at 1.25 waves/SIMD because its
// 32 KB buffer capped residency at 5 single-wave blocks/CU. Here: 128-thread
// blocks, wave w processes element b*2+w with R10's EXACT body (init, RY
// ladders, T1 transpose, merged diag, gray fold, epilogue all byte-identical).
// The buffer is time-shared: per layer each wave needs it only for two short
// sessions (T1: store+read ~830cyc; FOLD: fold-store+entry-load ~830cyc)
// versus ~7000cyc of register-only VALU. Token pattern per session pair:
//   bar; if(w==0) SESSION; bar; if(w==1) SESSION; <both continue VALU>
// Barriers are outside the wave-uniform branches (counts match -> no
// deadlock); intra-session store->read ordering is the wave's own
// s_waitcnt lgkmcnt(0) (no cross-wave sync needed: data is wave-private,
// barriers provide only mutual exclusion + prior-session drain).
// Grid 1024 blocks -> 4 blocks/CU resident (5 fit), 8 waves/CU = 2/SIMD:
// one wave's DS session hides under its SIMD-partner's VALU phase.
// ---------------------------------------------------------------------------

// ---- d_ws layout (float offsets) — identical to R10 (prep verified) ----
#define WS_WA0 0        // 64 f2 : init lane factor e^{i(phi0_lane - pi/2*pop)}
#define WS_Z0  128      // 64 f2 : init reg  factor e^{i(phi0_hi  - pi/2*pop)}
#define WS_W   256      // 5*64 f2 : merged diag lane factor (post-T1 lane)
#define WS_Z   896      // 5*2*64 f2 : merged diag reg table [l][h][p]
#define WS_RYT 2176     // 72 float4 : (c,c,s,s) per (l,wire)

typedef float f2 __attribute__((ext_vector_type(2)));

static __device__ __forceinline__ f2 pk_mul(f2 a, f2 b) {
  f2 d; asm("v_pk_mul_f32 %0, %1, %2" : "=v"(d) : "v"(a), "v"(b)); return d;
}
static __device__ __forceinline__ f2 pk_fma(f2 a, f2 b, f2 c) {
  f2 d; asm("v_pk_fma_f32 %0, %1, %2, %3" : "=v"(d) : "v"(a), "v"(b), "v"(c)); return d;
}
// complex mul, both operands packed (re,im)
static __device__ __forceinline__ f2 cmulp(f2 a, f2 c) {
  f2 r1, d;
  asm("v_pk_mul_f32 %0, %1, %2 op_sel:[0,0] op_sel_hi:[0,1]"
      : "=v"(r1) : "v"(a), "v"(c));
  asm("v_pk_fma_f32 %0, %1, %2, %3 op_sel:[1,1,0] op_sel_hi:[1,0,1] neg_lo:[1,0,0]"
      : "=v"(d) : "v"(a), "v"(c), "v"(r1));
  return d;
}

// RY pair update over 64 regs: a' = c*a - s*b ; b' = s*a + c*b (R10-verified)
template<int BIT>
static __device__ __forceinline__ void apply_ry64(f2 v[64], f2 cc, f2 ss) {
  #pragma unroll
  for (int j = 0; j < 64; ++j) {
    if (j & (1 << BIT)) continue;
    const int k = j | (1 << BIT);
    f2 a = v[j], b = v[k];
    f2 t1 = pk_mul(a, cc);
    f2 t2 = pk_mul(a, ss);
    f2 na; asm("v_pk_fma_f32 %0, %1, %2, %3 neg_lo:[1,0,0] neg_hi:[1,0,0]"
               : "=v"(na) : "v"(b), "v"(ss), "v"(t1));
    f2 nb = pk_fma(b, cc, t2);
    v[j] = na; v[k] = nb;
  }
}

// ---------------------------------------------------------------------------
// Prep kernel — verbatim R10 (numerically verified by R10's passing run).
// ---------------------------------------------------------------------------
__global__ __launch_bounds__(256)
void qprep_kernel(const float* __restrict__ w, float* __restrict__ ws) {
  const int t = threadIdx.x;
  const float HPI = 1.57079632679489662f;

  if (t < 64) {              // WA0[u], u = label bits 0..5 <-> wires 11..6
    const int u = t;
    float f = 0.f;
    #pragma unroll
    for (int k = 0; k < 6; ++k) {
      float p = w[(0*NQ + (11-k))*3 + 0];
      f += ((u >> k) & 1) ? 0.5f*p : -0.5f*p;
    }
    f -= HPI * (float)__popc(u);
    float sv, cv; sincosf(f, &sv, &cv);
    ws[WS_WA0 + 2*u] = cv; ws[WS_WA0 + 2*u + 1] = sv;
  } else if (t < 128) {      // Z0[p], p = label bits 6..11 <-> wires 5..0
    const int p_ = t - 64;
    float f = 0.f;
    #pragma unroll
    for (int k = 0; k < 6; ++k) {
      float p = w[(0*NQ + (5-k))*3 + 0];
      f += ((p_ >> k) & 1) ? 0.5f*p : -0.5f*p;
    }
    f -= HPI * (float)__popc(p_);
    float sv, cv; sincosf(f, &sv, &cv);
    ws[WS_Z0 + 2*p_] = cv; ws[WS_Z0 + 2*p_ + 1] = sv;
  }

  // W[l][u], u = post-T1 lane = label bits 6..11 (u_k <-> wire 5-k)
  for (int idx = t; idx < 5*64; idx += 256) {
    const int l = idx >> 6, u = idx & 63;
    float f = 0.f;
    #pragma unroll
    for (int k = 0; k < 6; ++k) {
      float om = w[(l*NQ + (5-k))*3 + 2];
      f += ((u >> k) & 1) ? 0.5f*om : -0.5f*om;
    }
    const int gu = u ^ (u >> 1);
    #pragma unroll
    for (int k = 0; k < 6; ++k) {
      float ph = w[((l+1)*NQ + (5-k))*3 + 0];
      f += ((gu >> k) & 1) ? 0.5f*ph : -0.5f*ph;
    }
    float sv, cv; sincosf(f, &sv, &cv);
    ws[WS_W + 2*idx] = cv; ws[WS_W + 2*idx + 1] = sv;
  }

  // Z[l][h][p], p = label bits 0..5 (p_k <-> wire 11-k), h = lam6
  for (int idx = t; idx < 5*2*64; idx += 256) {
    const int l = idx >> 7, h = (idx >> 6) & 1, p_ = idx & 63;
    float f = 0.f;
    #pragma unroll
    for (int k = 0; k < 6; ++k) {
      float om = w[(l*NQ + (11-k))*3 + 2];
      f += ((p_ >> k) & 1) ? 0.5f*om : -0.5f*om;
    }
    const int gp = (p_ ^ (p_ >> 1)) ^ (h << 5);
    #pragma unroll
    for (int k = 0; k < 6; ++k) {
      float ph = w[((l+1)*NQ + (11-k))*3 + 0];
      f += ((gp >> k) & 1) ? 0.5f*ph : -0.5f*ph;
    }
    float sv, cv; sincosf(f, &sv, &cv);
    ws[WS_Z + 2*idx] = cv; ws[WS_Z + 2*idx + 1] = sv;
  }

  if (t < NL*NQ) {           // ryt: (c,c,s,s) of theta/2 per (l,wire)
    float sv, cv; sincosf(0.5f*w[t*3 + 1], &sv, &cv);
    ((float4*)(ws + WS_RYT))[t] = make_float4(cv, cv, sv, sv);
  }
}

// Buffer sessions — R10's exact address math. Intra-session ordering is the
// issuing wave's own lgkmcnt drain; compiler reordering pinned by "memory".
#define T1_SESSION() do {                                                    \
    _Pragma("unroll")                                                        \
    for (int m = 0; m < 32; ++m) {                                           \
      const int idx = (2*m) ^ (L & 62);                                      \
      *(float4*)(stb + L*512 + (idx << 3)) =                                 \
          make_float4(v[2*m].x, v[2*m].y, v[2*m+1].x, v[2*m+1].y);           \
    }                                                                        \
    asm volatile("s_waitcnt lgkmcnt(0)" ::: "memory");                       \
    _Pragma("unroll")                                                        \
    for (int p = 0; p < 64; ++p)                                             \
      v[p] = *(const f2*)(stb + p*512 + ((L ^ (p & 62)) << 3));              \
  } while (0)

#define FOLD_SESSION() do {                                                  \
    const int Gh  = (L ^ (L >> 1)) & 63;                                     \
    const int hb5 = (L & 1) << 5;                                            \
    const int gsw = Gh & 62;                                                 \
    _Pragma("unroll")                                                        \
    for (int m = 0; m < 32; ++m) {                                           \
      const int glo0 = ((2*m) ^ m) ^ hb5;                                    \
      const int e_ = glo0 & ~1;                                              \
      float4 q4;                                                             \
      if (m & 1) q4 = make_float4(v[2*m+1].x, v[2*m+1].y, v[2*m].x, v[2*m].y);\
      else       q4 = make_float4(v[2*m].x, v[2*m].y, v[2*m+1].x, v[2*m+1].y);\
      *(float4*)(stb + Gh*512 + ((e_ ^ gsw) << 3)) = q4;                     \
    }                                                                        \
    asm volatile("s_waitcnt lgkmcnt(0)" ::: "memory");                       \
    _Pragma("unroll")                                                        \
    for (int r = 0; r < 64; ++r)                                             \
      v[r] = *(const f2*)(stb + r*512 + ((L ^ (r & 62)) << 3));              \
  } while (0)

// ---------------------------------------------------------------------------
// Main kernel: 2 waves/block, one element per wave, shared 32 KB buffer.
// ---------------------------------------------------------------------------
__global__ __launch_bounds__(TPB, 2)
void qsim12_kernel(const float* __restrict__ x, const float* __restrict__ ws,
                   float* __restrict__ out) {
  __shared__ __align__(16) float st[2*DIM];   // 32768 B, time-shared
  const int L = threadIdx.x & 63;             // lane within wave
  const int w = threadIdx.x >> 6;             // wave id 0/1
  const int e = blockIdx.x*2 + w;             // batch element of this wave
  char* stb = (char*)st;

  // x cos/sin: lanes 0..11 compute, readlane broadcast (per wave).
  float csx[NQ], csy[NQ];
  {
    float xv = (L < NQ) ? x[e*NQ + L] : 0.f;
    float sv, cv; sincosf(0.5f*xv, &sv, &cv);
    #pragma unroll
    for (int q = 0; q < NQ; ++q) {
      csx[q] = __int_as_float(__builtin_amdgcn_readlane(__float_as_int(cv), q));
      csy[q] = __int_as_float(__builtin_amdgcn_readlane(__float_as_int(sv), q));
    }
  }

  f2 v[64];

  // ---- Init (A-storage, R10-verbatim): v[p]@lane L = element(hi=p, lo=L)
  {
    float rl = 1.f;
    #pragma unroll
    for (int k = 0; k < 6; ++k)
      rl *= ((L >> k) & 1) ? csy[11-k] : csx[11-k];
    float mlo[8], mhi[8];
    #pragma unroll
    for (int pm = 0; pm < 8; ++pm) {
      float a = ((pm >> 0) & 1) ? csy[5] : csx[5];
      a *= ((pm >> 1) & 1) ? csy[4] : csx[4];
      a *= ((pm >> 2) & 1) ? csy[3] : csx[3];
      mlo[pm] = a;
      float bb = ((pm >> 0) & 1) ? csy[2] : csx[2];
      bb *= ((pm >> 1) & 1) ? csy[1] : csx[1];
      bb *= ((pm >> 2) & 1) ? csy[0] : csx[0];
      mhi[pm] = bb;
    }
    const float2 wv = *(const float2*)(ws + WS_WA0 + 2*L);
    const f2 a0 = (f2){wv.x*rl, wv.y*rl};
    #pragma unroll
    for (int p = 0; p < 64; ++p) {
      const float2 zv = *(const float2*)(ws + WS_Z0 + 2*p);
      f2 ph = cmulp(a0, (f2){zv.x, zv.y});
      const float m = mlo[p & 7] * mhi[p >> 3];
      v[p] = pk_mul(ph, (f2){m, m});
    }
  }

  #define RY6(BIT, WQ) { const float4 r = *(const float4*)(ws + WS_RYT + 4*(l*NQ + (WQ))); \
      apply_ry64<BIT>(v, (f2){r.x, r.y}, (f2){r.z, r.w}); }

  #pragma unroll 1
  for (int l = 0; l < NL; ++l) {
    // h1: wires 5..0 (reg bits); entry state already in regs (init or FOLD)
    RY6(0,5) RY6(1,4) RY6(2,3) RY6(3,2) RY6(4,1) RY6(5,0)

    // T1 transpose, token-serialized on the shared buffer
    __syncthreads();                 // (1) prior sessions fully drained
    if (w == 0) T1_SESSION();
    __syncthreads();                 // (2) w0's reads done before w1's stores
    if (w == 1) T1_SESSION();        //     runs under w0's h2 below

    // h2: wires 11..6 (reg bits post-transpose)
    RY6(0,11) RY6(1,10) RY6(2,9) RY6(3,8) RY6(4,7) RY6(5,6)

    if (l < NL-1) {
      // merged diag D_om(l)*D_phi(l+1) at post-CNOT label gray(lambda)
      const float2 wv = *(const float2*)(ws + WS_W + (l*64 + L)*2);
      const f2 W = (f2){wv.x, wv.y};
      const float* zb = ws + WS_Z + ((l*2 + (L & 1))*64)*2;
      #pragma unroll
      for (int p0 = 0; p0 < 64; p0 += 8) {
        f2 z[8];
        #pragma unroll
        for (int q = 0; q < 8; ++q) {
          const float2 zv = *(const float2*)(zb + 2*(p0+q));
          z[q] = (f2){zv.x, zv.y};
        }
        #pragma unroll
        for (int q = 0; q < 8; ++q)
          v[p0+q] = cmulp(cmulp(v[p0+q], z[q]), W);
      }

      // fold-store + entry-load(l+1), token-serialized
      __syncthreads();               // (3)
      if (w == 0) FOLD_SESSION();
      __syncthreads();               // (4)
      if (w == 1) FOLD_SESSION();    //     runs under w0's next h1
    }
  }

  // ---- Epilogue (B-storage: lane = label bits 6..11), R10-verbatim.
  float ssum = 0.f;
  #pragma unroll
  for (int p = 0; p < 64; ++p)
    ssum += v[p].x*v[p].x + v[p].y*v[p].y;
  float s0 = ((L >> 5) & 1) ? -ssum : ssum;
  float s1 = (((L >> 4) ^ (L >> 5)) & 1) ? -ssum : ssum;
  #pragma unroll
  for (int off = 32; off >= 1; off >>= 1) {
    s0 += __shfl_down(s0, off);
    s1 += __shfl_down(s1, off);
  }
  if (L == 0) { out[e*2 + 0] = s0; out[e*2 + 1] = s1; }
}

extern "C" void kernel_launch(void* const* d_in, const int* in_sizes, int n_in,
                              void* d_out, int out_size, void* d_ws, size_t ws_size,
                              hipStream_t stream) {
  const float* x = (const float*)d_in[0];      // (B, 12) f32
  const float* w = (const float*)d_in[1];      // (6, 12, 3) f32
  float* out = (float*)d_out;                  // (B, 2) f32
  float* ws = (float*)d_ws;                    // needs >= 9856 B
  int B = in_sizes[0] / NQ;                    // B = 2048 (even)
  qprep_kernel<<<1, 256, 0, stream>>>(w, ws);
  qsim12_kernel<<<B/2, TPB, 0, stream>>>(x, ws, out);
}